// Round 1
// baseline (584.315 us; speedup 1.0000x reference)
//
#include <hip/hip_runtime.h>
#include <math.h>

#define N_NODES 10000
#define N_EDGES 320000
#define IN_FEATS 512
#define N_UNITS 256
#define OUT_FEATS 64
#define N_HID 5  // hidden Wh layers

// ---------------- CSR build ----------------

__global__ void k_hist(const int* __restrict__ dst, int* __restrict__ deg) {
    int e = blockIdx.x * blockDim.x + threadIdx.x;
    if (e < N_EDGES) atomicAdd(&deg[dst[e]], 1);
}

// single-block exclusive scan over deg -> row_ptr (+cursor copy) + dinv/invdeg
__global__ __launch_bounds__(1024) void k_scan(const int* __restrict__ deg,
                                               int* __restrict__ row_ptr,
                                               int* __restrict__ cursor,
                                               float* __restrict__ dinv,
                                               float* __restrict__ invdeg) {
    __shared__ int carry;
    __shared__ int buf[1024];
    int t = threadIdx.x;
    if (t == 0) carry = 0;
    __syncthreads();
    for (int base = 0; base < N_NODES; base += 1024) {
        int i = base + t;
        int v = (i < N_NODES) ? deg[i] : 0;
        buf[t] = v;
        __syncthreads();
        for (int off = 1; off < 1024; off <<= 1) {
            int x = (t >= off) ? buf[t - off] : 0;
            __syncthreads();
            buf[t] += x;
            __syncthreads();
        }
        int excl = buf[t] - v;
        int c = carry;
        if (i < N_NODES) {
            int rp = c + excl;
            row_ptr[i] = rp;
            cursor[i]  = rp;
            float d = (float)(v + 1);
            dinv[i]   = rsqrtf(d);
            invdeg[i] = 1.0f / d;
        }
        __syncthreads();
        if (t == 1023) carry = c + buf[1023];
        __syncthreads();
    }
    if (t == 0) row_ptr[N_NODES] = carry;
}

__global__ void k_fill(const int* __restrict__ src, const int* __restrict__ dst,
                       int* __restrict__ cursor, int* __restrict__ csr_src) {
    int e = blockIdx.x * blockDim.x + threadIdx.x;
    if (e < N_EDGES) {
        int p = atomicAdd(&cursor[dst[e]], 1);
        csr_src[p] = src[e];
    }
}

// ---------------- fp32 tiled GEMM: C[M,N] = A[M,K] @ B[K,N] ----------------
// 64x64 block tile, 16 K-tile, 256 threads, 4x4 microtile.

#define BM 64
#define BN 64
#define BK 16

__global__ __launch_bounds__(256) void k_gemm(const float* __restrict__ A,
                                              const float* __restrict__ B,
                                              float* __restrict__ C,
                                              int M, int N, int K) {
    __shared__ float As[BK][BM + 1];
    __shared__ float Bs[BK][BN];

    int tid  = threadIdx.x;
    int brow = blockIdx.x * BM;
    int bcol = blockIdx.y * BN;

    int tx = tid & 15;   // col group
    int ty = tid >> 4;   // row group

    // A-load mapping: 256 threads x float4 covers 64x16
    int a_row = tid >> 2;          // 0..63
    int a_c4  = (tid & 3) * 4;     // 0,4,8,12
    // B-load mapping: 16x64
    int b_row = tid >> 4;          // 0..15
    int b_c4  = (tid & 15) * 4;    // 0..60

    float acc[4][4] = {};

    for (int k0 = 0; k0 < K; k0 += BK) {
        // load A tile (guard M edge)
        int gr = brow + a_row;
        float4 av;
        if (gr < M) {
            av = *reinterpret_cast<const float4*>(&A[(size_t)gr * K + k0 + a_c4]);
        } else {
            av = make_float4(0.f, 0.f, 0.f, 0.f);
        }
        // load B tile
        float4 bv = *reinterpret_cast<const float4*>(&B[(size_t)(k0 + b_row) * N + bcol + b_c4]);

        As[a_c4 + 0][a_row] = av.x;
        As[a_c4 + 1][a_row] = av.y;
        As[a_c4 + 2][a_row] = av.z;
        As[a_c4 + 3][a_row] = av.w;
        *reinterpret_cast<float4*>(&Bs[b_row][b_c4]) = bv;
        __syncthreads();

#pragma unroll
        for (int k = 0; k < BK; ++k) {
            float a[4], b[4];
#pragma unroll
            for (int i = 0; i < 4; ++i) a[i] = As[k][ty + 16 * i];
#pragma unroll
            for (int j = 0; j < 4; ++j) b[j] = Bs[k][tx + 16 * j];
#pragma unroll
            for (int i = 0; i < 4; ++i)
#pragma unroll
                for (int j = 0; j < 4; ++j)
                    acc[i][j] += a[i] * b[j];
        }
        __syncthreads();
    }

#pragma unroll
    for (int i = 0; i < 4; ++i) {
        int r = brow + ty + 16 * i;
        if (r < M) {
#pragma unroll
            for (int j = 0; j < 4; ++j) {
                C[(size_t)r * N + bcol + tx + 16 * j] = acc[i][j];
            }
        }
    }
}

// ---------------- CSR aggregation + bias + relu + running JK max ----------------
// one block (256 threads) per node, feature dim = 256

__global__ __launch_bounds__(256) void k_agg(const float* __restrict__ m,
                                             const int* __restrict__ row_ptr,
                                             const int* __restrict__ csr_src,
                                             const float* __restrict__ bias,
                                             float* __restrict__ x_out,
                                             float* __restrict__ jk,
                                             int init_jk) {
    int n = blockIdx.x;
    int f = threadIdx.x;
    int s = row_ptr[n], e = row_ptr[n + 1];

    float acc = 0.f;
    int i = s;
    for (; i + 3 < e; i += 4) {
        int s0 = csr_src[i], s1 = csr_src[i + 1], s2 = csr_src[i + 2], s3 = csr_src[i + 3];
        float v0 = m[(size_t)s0 * N_UNITS + f];
        float v1 = m[(size_t)s1 * N_UNITS + f];
        float v2 = m[(size_t)s2 * N_UNITS + f];
        float v3 = m[(size_t)s3 * N_UNITS + f];
        acc += v0 + v1 + v2 + v3;
    }
    for (; i < e; ++i) acc += m[(size_t)csr_src[i] * N_UNITS + f];

    acc += bias[f];
    acc = fmaxf(acc, 0.f);
    x_out[(size_t)n * N_UNITS + f] = acc;
    if (init_jk) jk[(size_t)n * N_UNITS + f] = acc;
    else         jk[(size_t)n * N_UNITS + f] = fmaxf(jk[(size_t)n * N_UNITS + f], acc);
}

// ---------------- final GCN-norm agg + self loop + bias + log_softmax ----------------
// one wave (64 lanes) per node; 64 features

__global__ __launch_bounds__(256) void k_final(const float* __restrict__ mf,
                                               const int* __restrict__ row_ptr,
                                               const int* __restrict__ csr_src,
                                               const float* __restrict__ dinv,
                                               const float* __restrict__ invdeg,
                                               const float* __restrict__ bo,
                                               float* __restrict__ out) {
    int wid  = threadIdx.x >> 6;
    int lane = threadIdx.x & 63;
    int n = blockIdx.x * 4 + wid;
    if (n >= N_NODES) return;

    int s = row_ptr[n], e = row_ptr[n + 1];
    float acc = 0.f;
    for (int i = s; i < e; ++i) {
        int sr = csr_src[i];
        acc += mf[(size_t)sr * OUT_FEATS + lane] * dinv[sr];
    }
    acc *= dinv[n];
    acc += mf[(size_t)n * OUT_FEATS + lane] * invdeg[n] + bo[lane];

    // log_softmax over 64 lanes
    float mx = acc;
#pragma unroll
    for (int off = 32; off; off >>= 1) mx = fmaxf(mx, __shfl_xor(mx, off));
    float ex = __expf(acc - mx);
    float sum = ex;
#pragma unroll
    for (int off = 32; off; off >>= 1) sum += __shfl_xor(sum, off);
    out[(size_t)n * OUT_FEATS + lane] = acc - mx - __logf(sum);
}

// ---------------- launch ----------------

extern "C" void kernel_launch(void* const* d_in, const int* in_sizes, int n_in,
                              void* d_out, int out_size, void* d_ws, size_t ws_size,
                              hipStream_t stream) {
    const float* h  = (const float*)d_in[0];
    const int*   ei = (const int*)d_in[1];
    const float* W0 = (const float*)d_in[2];
    const float* b0 = (const float*)d_in[3];
    const float* Wh = (const float*)d_in[4];
    const float* bh = (const float*)d_in[5];
    const float* Wo = (const float*)d_in[6];
    const float* bo = (const float*)d_in[7];

    const int* src = ei;            // edge_index[0]
    const int* dst = ei + N_EDGES;  // edge_index[1]

    // workspace carve (256B aligned)
    char* p = (char*)d_ws;
    auto carve = [&](size_t bytes) {
        char* r = p;
        p += (bytes + 255) & ~(size_t)255;
        return r;
    };
    int*   deg     = (int*)  carve(N_NODES * 4);
    int*   row_ptr = (int*)  carve((N_NODES + 1) * 4);
    int*   cursor  = (int*)  carve(N_NODES * 4);
    int*   csr_src = (int*)  carve(N_EDGES * 4);
    float* dinv    = (float*)carve(N_NODES * 4);
    float* invdeg  = (float*)carve(N_NODES * 4);
    float* m       = (float*)carve((size_t)N_NODES * N_UNITS * 4);
    float* x       = (float*)carve((size_t)N_NODES * N_UNITS * 4);
    float* jk      = (float*)carve((size_t)N_NODES * N_UNITS * 4);
    float* mf      = (float*)carve((size_t)N_NODES * OUT_FEATS * 4);

    hipMemsetAsync(deg, 0, N_NODES * 4, stream);
    k_hist<<<(N_EDGES + 255) / 256, 256, 0, stream>>>(dst, deg);
    k_scan<<<1, 1024, 0, stream>>>(deg, row_ptr, cursor, dinv, invdeg);
    k_fill<<<(N_EDGES + 255) / 256, 256, 0, stream>>>(src, dst, cursor, csr_src);

    dim3 blk(256);
    // layer 0: m = h @ W0
    {
        dim3 g((N_NODES + BM - 1) / BM, N_UNITS / BN);
        k_gemm<<<g, blk, 0, stream>>>(h, W0, m, N_NODES, N_UNITS, IN_FEATS);
    }
    k_agg<<<N_NODES, 256, 0, stream>>>(m, row_ptr, csr_src, b0, x, jk, 1);

    // hidden layers
    for (int l = 0; l < N_HID; ++l) {
        dim3 g((N_NODES + BM - 1) / BM, N_UNITS / BN);
        k_gemm<<<g, blk, 0, stream>>>(x, Wh + (size_t)l * N_UNITS * N_UNITS, m,
                                      N_NODES, N_UNITS, N_UNITS);
        k_agg<<<N_NODES, 256, 0, stream>>>(m, row_ptr, csr_src, bh + (size_t)l * N_UNITS,
                                           x, jk, 0);
    }

    // final: mf = jk @ Wo
    {
        dim3 g((N_NODES + BM - 1) / BM, OUT_FEATS / BN);
        k_gemm<<<g, blk, 0, stream>>>(jk, Wo, mf, N_NODES, OUT_FEATS, N_UNITS);
    }
    k_final<<<(N_NODES + 3) / 4, 256, 0, stream>>>(mf, row_ptr, csr_src, dinv, invdeg,
                                                   bo, (float*)d_out);
}

// Round 2
// 383.576 us; speedup vs baseline: 1.5233x; 1.5233x over previous
//
#include <hip/hip_runtime.h>
#include <math.h>

#define N_NODES 10000
#define N_EDGES 320000
#define IN_FEATS 512
#define N_UNITS 256
#define OUT_FEATS 64
#define N_HID 5  // hidden Wh layers

typedef __attribute__((ext_vector_type(8))) short bf16x8;
typedef __attribute__((ext_vector_type(4))) float f32x4;

__device__ __forceinline__ unsigned short f2bf(float f) {
    union { float f; unsigned int u; } c; c.f = f;
    unsigned int u = c.u + 0x7FFFu + ((c.u >> 16) & 1u);  // RNE
    return (unsigned short)(u >> 16);
}
__device__ __forceinline__ float bf2f(unsigned short b) {
    union { unsigned int u; float f; } c; c.u = ((unsigned int)b) << 16;
    return c.f;
}

// ---------------- CSR build ----------------

__global__ void k_hist(const int* __restrict__ dst, int* __restrict__ deg) {
    int e = blockIdx.x * blockDim.x + threadIdx.x;
    if (e < N_EDGES) atomicAdd(&deg[dst[e]], 1);
}

__global__ __launch_bounds__(1024) void k_scan(const int* __restrict__ deg,
                                               int* __restrict__ row_ptr,
                                               int* __restrict__ cursor,
                                               float* __restrict__ dinv,
                                               float* __restrict__ invdeg) {
    __shared__ int carry;
    __shared__ int buf[1024];
    int t = threadIdx.x;
    if (t == 0) carry = 0;
    __syncthreads();
    for (int base = 0; base < N_NODES; base += 1024) {
        int i = base + t;
        int v = (i < N_NODES) ? deg[i] : 0;
        buf[t] = v;
        __syncthreads();
        for (int off = 1; off < 1024; off <<= 1) {
            int x = (t >= off) ? buf[t - off] : 0;
            __syncthreads();
            buf[t] += x;
            __syncthreads();
        }
        int excl = buf[t] - v;
        int c = carry;
        if (i < N_NODES) {
            int rp = c + excl;
            row_ptr[i] = rp;
            cursor[i]  = rp;
            float d = (float)(v + 1);
            dinv[i]   = rsqrtf(d);
            invdeg[i] = 1.0f / d;
        }
        __syncthreads();
        if (t == 1023) carry = c + buf[1023];
        __syncthreads();
    }
    if (t == 0) row_ptr[N_NODES] = carry;
}

__global__ void k_fill(const int* __restrict__ src, const int* __restrict__ dst,
                       int* __restrict__ cursor, int* __restrict__ csr_src) {
    int e = blockIdx.x * blockDim.x + threadIdx.x;
    if (e < N_EDGES) {
        int p = atomicAdd(&cursor[dst[e]], 1);
        csr_src[p] = src[e];
    }
}

// ---------------- converts ----------------

// h fp32 -> bf16, vectorized by 4
__global__ void k_cvth(const float* __restrict__ h, unsigned short* __restrict__ hb) {
    int t = blockIdx.x * blockDim.x + threadIdx.x;
    if (t < N_NODES * IN_FEATS / 4) {
        float4 v = reinterpret_cast<const float4*>(h)[t];
        ushort4 o;
        o.x = f2bf(v.x); o.y = f2bf(v.y); o.z = f2bf(v.z); o.w = f2bf(v.w);
        reinterpret_cast<ushort4*>(hb)[t] = o;
    }
}

// all weights fp32 -> bf16 transposed ([K][N] -> [N][K])
__global__ void k_cvtw(const float* __restrict__ W0, const float* __restrict__ Wh,
                       const float* __restrict__ Wo,
                       unsigned short* __restrict__ W0t, unsigned short* __restrict__ Wht,
                       unsigned short* __restrict__ Wot) {
    int t = blockIdx.x * blockDim.x + threadIdx.x;
    const int S0 = IN_FEATS * N_UNITS;                 // 131072
    const int SH = N_HID * N_UNITS * N_UNITS;          // 327680
    const int SO = N_UNITS * OUT_FEATS;                // 16384
    if (t < S0) {
        int k = t >> 8, n = t & 255;
        W0t[(size_t)n * IN_FEATS + k] = f2bf(W0[t]);
    } else if (t < S0 + SH) {
        int u = t - S0;
        int l = u >> 16;           // 256*256 = 65536 per layer
        int r = u & 65535;
        int k = r >> 8, n = r & 255;
        Wht[(size_t)l * 65536 + (size_t)n * N_UNITS + k] = f2bf(Wh[u]);
    } else if (t < S0 + SH + SO) {
        int u = t - S0 - SH;
        int k = u >> 6, n = u & 63;
        Wot[(size_t)n * N_UNITS + k] = f2bf(Wo[u]);
    }
}

// ---------------- bf16 MFMA GEMM: C[M,N] = A[M,K] @ Bt[N,K]^T ----------------
// BM=128, BK=32, 256 threads = 4 waves in 2x2, each wave 64 x (BN/2).
// A and Bt both row-major [rows][K] bf16; fragments read as contiguous b128.

template<int BN, int FN, bool OUT_BF16>
__global__ __launch_bounds__(256) void k_mgemm(const unsigned short* __restrict__ A,
                                               const unsigned short* __restrict__ Bt,
                                               void* __restrict__ Cv,
                                               const int M, const int K, const int Nld) {
    constexpr int BM = 128, BK = 32;
    constexpr int WN = BN / 2;
    __shared__ unsigned short As[BM * BK];
    __shared__ unsigned short Bs[BN * BK];

    const int tid  = threadIdx.x;
    const int wid  = tid >> 6;
    const int lane = tid & 63;
    const int wr   = wid >> 1;       // 0..1
    const int wc   = wid & 1;        // 0..1
    const int brow = blockIdx.x * BM;
    const int bcol = blockIdx.y * BN;

    const int lr = lane & 15;        // row within fragment
    const int lk = lane >> 4;        // k-group (x8)

    f32x4 acc[4][FN];
#pragma unroll
    for (int m = 0; m < 4; ++m)
#pragma unroll
        for (int n = 0; n < FN; ++n)
            acc[m][n] = (f32x4){0.f, 0.f, 0.f, 0.f};

    for (int k0 = 0; k0 < K; k0 += BK) {
        // stage A tile [BM][BK]: BM*64 bytes, 16B per lane-op
#pragma unroll
        for (int p = 0; p < BM / 64; ++p) {
            int i = p * 256 + tid;           // 16B slot index
            int row = i >> 2, slot = i & 3;
            int gr = brow + row; if (gr >= M) gr = M - 1;
            const unsigned short* gp = A + (size_t)gr * K + k0 + slot * 8;
            __builtin_amdgcn_global_load_lds(
                (const __attribute__((address_space(1))) void*)gp,
                (__attribute__((address_space(3))) void*)(As + i * 8), 16, 0, 0);
        }
        // stage Bt tile [BN][BK]
#pragma unroll
        for (int p = 0; p < BN / 64; ++p) {
            int i = p * 256 + tid;
            int row = i >> 2, slot = i & 3;
            const unsigned short* gp = Bt + (size_t)(bcol + row) * K + k0 + slot * 8;
            __builtin_amdgcn_global_load_lds(
                (const __attribute__((address_space(1))) void*)gp,
                (__attribute__((address_space(3))) void*)(Bs + i * 8), 16, 0, 0);
        }
        __syncthreads();

        bf16x8 af[4], bfr[FN];
#pragma unroll
        for (int m = 0; m < 4; ++m)
            af[m] = *reinterpret_cast<const bf16x8*>(&As[(wr * 64 + m * 16 + lr) * BK + lk * 8]);
#pragma unroll
        for (int n = 0; n < FN; ++n)
            bfr[n] = *reinterpret_cast<const bf16x8*>(&Bs[(wc * WN + n * 16 + lr) * BK + lk * 8]);
#pragma unroll
        for (int m = 0; m < 4; ++m)
#pragma unroll
            for (int n = 0; n < FN; ++n)
                acc[m][n] = __builtin_amdgcn_mfma_f32_16x16x32_bf16(af[m], bfr[n], acc[m][n], 0, 0, 0);
        __syncthreads();
    }

    // epilogue: D row = (lane>>4)*4 + r, col = lane&15
#pragma unroll
    for (int m = 0; m < 4; ++m) {
#pragma unroll
        for (int r = 0; r < 4; ++r) {
            int row = brow + wr * 64 + m * 16 + lk * 4 + r;
            if (row < M) {
#pragma unroll
                for (int n = 0; n < FN; ++n) {
                    int col = bcol + wc * WN + n * 16 + lr;
                    float v = acc[m][n][r];
                    if (OUT_BF16)
                        ((unsigned short*)Cv)[(size_t)row * Nld + col] = f2bf(v);
                    else
                        ((float*)Cv)[(size_t)row * Nld + col] = v;
                }
            }
        }
    }
}

// ---------------- CSR aggregation + bias + relu + running JK max (bf16 IO) ----------------

__global__ __launch_bounds__(256) void k_agg(const unsigned short* __restrict__ m,
                                             const int* __restrict__ row_ptr,
                                             const int* __restrict__ csr_src,
                                             const float* __restrict__ bias,
                                             unsigned short* __restrict__ x_out,
                                             unsigned short* __restrict__ jk,
                                             int init_jk) {
    int n = blockIdx.x;
    int f = threadIdx.x;
    int s = row_ptr[n], e = row_ptr[n + 1];

    float acc = 0.f;
    int i = s;
    for (; i + 3 < e; i += 4) {
        int s0 = csr_src[i], s1 = csr_src[i + 1], s2 = csr_src[i + 2], s3 = csr_src[i + 3];
        float v0 = bf2f(m[(size_t)s0 * N_UNITS + f]);
        float v1 = bf2f(m[(size_t)s1 * N_UNITS + f]);
        float v2 = bf2f(m[(size_t)s2 * N_UNITS + f]);
        float v3 = bf2f(m[(size_t)s3 * N_UNITS + f]);
        acc += v0 + v1 + v2 + v3;
    }
    for (; i < e; ++i) acc += bf2f(m[(size_t)csr_src[i] * N_UNITS + f]);

    acc += bias[f];
    acc = fmaxf(acc, 0.f);
    unsigned short xb = f2bf(acc);
    size_t idx = (size_t)n * N_UNITS + f;
    x_out[idx] = xb;
    if (init_jk) {
        jk[idx] = xb;
    } else {
        unsigned short jb = jk[idx];
        if (bf2f(xb) > bf2f(jb)) jk[idx] = xb;
    }
}

// ---------------- final GCN-norm agg + self loop + bias + log_softmax ----------------

__global__ __launch_bounds__(256) void k_final(const float* __restrict__ mf,
                                               const int* __restrict__ row_ptr,
                                               const int* __restrict__ csr_src,
                                               const float* __restrict__ dinv,
                                               const float* __restrict__ invdeg,
                                               const float* __restrict__ bo,
                                               float* __restrict__ out) {
    int wid  = threadIdx.x >> 6;
    int lane = threadIdx.x & 63;
    int n = blockIdx.x * 4 + wid;
    if (n >= N_NODES) return;

    int s = row_ptr[n], e = row_ptr[n + 1];
    float acc = 0.f;
    for (int i = s; i < e; ++i) {
        int sr = csr_src[i];
        acc += mf[(size_t)sr * OUT_FEATS + lane] * dinv[sr];
    }
    acc *= dinv[n];
    acc += mf[(size_t)n * OUT_FEATS + lane] * invdeg[n] + bo[lane];

    float mx = acc;
#pragma unroll
    for (int off = 32; off; off >>= 1) mx = fmaxf(mx, __shfl_xor(mx, off));
    float ex = __expf(acc - mx);
    float sum = ex;
#pragma unroll
    for (int off = 32; off; off >>= 1) sum += __shfl_xor(sum, off);
    out[(size_t)n * OUT_FEATS + lane] = acc - mx - __logf(sum);
}

// ---------------- launch ----------------

extern "C" void kernel_launch(void* const* d_in, const int* in_sizes, int n_in,
                              void* d_out, int out_size, void* d_ws, size_t ws_size,
                              hipStream_t stream) {
    const float* h  = (const float*)d_in[0];
    const int*   ei = (const int*)d_in[1];
    const float* W0 = (const float*)d_in[2];
    const float* b0 = (const float*)d_in[3];
    const float* Wh = (const float*)d_in[4];
    const float* bh = (const float*)d_in[5];
    const float* Wo = (const float*)d_in[6];
    const float* bo = (const float*)d_in[7];

    const int* src = ei;
    const int* dst = ei + N_EDGES;

    char* p = (char*)d_ws;
    auto carve = [&](size_t bytes) {
        char* r = p;
        p += (bytes + 255) & ~(size_t)255;
        return r;
    };
    int*   deg     = (int*)  carve(N_NODES * 4);
    int*   row_ptr = (int*)  carve((N_NODES + 1) * 4);
    int*   cursor  = (int*)  carve(N_NODES * 4);
    int*   csr_src = (int*)  carve(N_EDGES * 4);
    float* dinv    = (float*)carve(N_NODES * 4);
    float* invdeg  = (float*)carve(N_NODES * 4);
    unsigned short* hb  = (unsigned short*)carve((size_t)N_NODES * IN_FEATS * 2);
    unsigned short* W0t = (unsigned short*)carve((size_t)IN_FEATS * N_UNITS * 2);
    unsigned short* Wht = (unsigned short*)carve((size_t)N_HID * N_UNITS * N_UNITS * 2);
    unsigned short* Wot = (unsigned short*)carve((size_t)N_UNITS * OUT_FEATS * 2);
    unsigned short* m   = (unsigned short*)carve((size_t)N_NODES * N_UNITS * 2);
    unsigned short* x   = (unsigned short*)carve((size_t)N_NODES * N_UNITS * 2);
    unsigned short* jk  = (unsigned short*)carve((size_t)N_NODES * N_UNITS * 2);
    float* mf = (float*)carve((size_t)N_NODES * OUT_FEATS * 4);

    hipMemsetAsync(deg, 0, N_NODES * 4, stream);
    k_hist<<<(N_EDGES + 255) / 256, 256, 0, stream>>>(dst, deg);
    k_scan<<<1, 1024, 0, stream>>>(deg, row_ptr, cursor, dinv, invdeg);
    k_fill<<<(N_EDGES + 255) / 256, 256, 0, stream>>>(src, dst, cursor, csr_src);

    k_cvth<<<(N_NODES * IN_FEATS / 4 + 255) / 256, 256, 0, stream>>>(h, hb);
    {
        int total = IN_FEATS * N_UNITS + N_HID * N_UNITS * N_UNITS + N_UNITS * OUT_FEATS;
        k_cvtw<<<(total + 255) / 256, 256, 0, stream>>>(W0, Wh, Wo, W0t, Wht, Wot);
    }

    const int GBM = (N_NODES + 127) / 128;  // 79

    // layer 0: m = hb @ W0t^T   [10000x512]x[512x256]
    {
        dim3 g(GBM, N_UNITS / 128);
        k_mgemm<128, 4, true><<<g, 256, 0, stream>>>(hb, W0t, m, N_NODES, IN_FEATS, N_UNITS);
    }
    k_agg<<<N_NODES, 256, 0, stream>>>(m, row_ptr, csr_src, b0, x, jk, 1);

    for (int l = 0; l < N_HID; ++l) {
        dim3 g(GBM, N_UNITS / 128);
        k_mgemm<128, 4, true><<<g, 256, 0, stream>>>(x, Wht + (size_t)l * N_UNITS * N_UNITS,
                                                     m, N_NODES, N_UNITS, N_UNITS);
        k_agg<<<N_NODES, 256, 0, stream>>>(m, row_ptr, csr_src, bh + (size_t)l * N_UNITS,
                                           x, jk, 0);
    }

    // final: mf = jk @ Wot^T  [10000x256]x[256x64], fp32 out
    {
        dim3 g(GBM, 1);
        k_mgemm<64, 2, false><<<g, 256, 0, stream>>>(jk, Wot, mf, N_NODES, N_UNITS, OUT_FEATS);
    }
    k_final<<<(N_NODES + 3) / 4, 256, 0, stream>>>(mf, row_ptr, csr_src, dinv, invdeg,
                                                   bo, (float*)d_out);
}

// Round 3
// 264.182 us; speedup vs baseline: 2.2118x; 1.4519x over previous
//
#include <hip/hip_runtime.h>
#include <math.h>

#define N_NODES 10000
#define N_EDGES 320000
#define IN_FEATS 512
#define N_UNITS 256
#define OUT_FEATS 64
#define N_HID 5  // hidden Wh layers

typedef __attribute__((ext_vector_type(8))) short bf16x8;
typedef __attribute__((ext_vector_type(4))) float f32x4;

__device__ __forceinline__ unsigned short f2bf(float f) {
    union { float f; unsigned int u; } c; c.f = f;
    unsigned int u = c.u + 0x7FFFu + ((c.u >> 16) & 1u);  // RNE
    return (unsigned short)(u >> 16);
}
__device__ __forceinline__ float bf2f(unsigned short b) {
    union { unsigned int u; float f; } c; c.u = ((unsigned int)b) << 16;
    return c.f;
}

// ---------------- CSR build ----------------

__global__ void k_hist(const int* __restrict__ dst, int* __restrict__ deg) {
    int e = blockIdx.x * blockDim.x + threadIdx.x;
    if (e < N_EDGES) atomicAdd(&deg[dst[e]], 1);
}

// one 1024-thread block; 10 elements per thread; 3 barriers total
__global__ __launch_bounds__(1024) void k_scan(const int* __restrict__ deg,
                                               int* __restrict__ row_ptr,
                                               int* __restrict__ cursor,
                                               float* __restrict__ dinv,
                                               float* __restrict__ invdeg) {
    __shared__ int wsum[16];
    const int PER = 10;
    int t = threadIdx.x;
    int lane = t & 63, wid = t >> 6;
    int base = t * PER;

    int v[PER];  // exclusive local prefix
    int s = 0;
#pragma unroll
    for (int j = 0; j < PER; ++j) {
        int i = base + j;
        int d = (i < N_NODES) ? deg[i] : 0;
        v[j] = s;
        s += d;
    }
    // inclusive wave scan of per-thread sums
    int inc = s;
#pragma unroll
    for (int off = 1; off < 64; off <<= 1) {
        int y = __shfl_up(inc, off);
        if (lane >= off) inc += y;
    }
    if (lane == 63) wsum[wid] = inc;
    __syncthreads();
    if (wid == 0) {
        int w = (lane < 16) ? wsum[lane] : 0;
#pragma unroll
        for (int off = 1; off < 16; off <<= 1) {
            int y = __shfl_up(w, off);
            if (lane >= off) w += y;
        }
        if (lane < 16) wsum[lane] = w;  // inclusive wave sums
    }
    __syncthreads();
    int wave_excl = (wid == 0) ? 0 : wsum[wid - 1];
    int thread_excl = wave_excl + (inc - s);

#pragma unroll
    for (int j = 0; j < PER; ++j) {
        int i = base + j;
        if (i < N_NODES) {
            int rp = thread_excl + v[j];
            row_ptr[i] = rp;
            cursor[i]  = rp;
            int d = ((j + 1 < PER) ? v[j + 1] : s) - v[j];
            float dd = (float)(d + 1);
            dinv[i]   = rsqrtf(dd);
            invdeg[i] = 1.0f / dd;
        }
    }
    if (t == 1023) row_ptr[N_NODES] = thread_excl + s;
}

__global__ void k_fill(const int* __restrict__ src, const int* __restrict__ dst,
                       int* __restrict__ cursor, int* __restrict__ csr_src) {
    int e = blockIdx.x * blockDim.x + threadIdx.x;
    if (e < N_EDGES) {
        int p = atomicAdd(&cursor[dst[e]], 1);
        csr_src[p] = src[e];
    }
}

// ---------------- converts ----------------

__global__ void k_cvth(const float* __restrict__ h, unsigned short* __restrict__ hb) {
    int t = blockIdx.x * blockDim.x + threadIdx.x;
    if (t < N_NODES * IN_FEATS / 4) {
        float4 v = reinterpret_cast<const float4*>(h)[t];
        ushort4 o;
        o.x = f2bf(v.x); o.y = f2bf(v.y); o.z = f2bf(v.z); o.w = f2bf(v.w);
        reinterpret_cast<ushort4*>(hb)[t] = o;
    }
}

__global__ void k_cvtw(const float* __restrict__ W0, const float* __restrict__ Wh,
                       const float* __restrict__ Wo,
                       unsigned short* __restrict__ W0t, unsigned short* __restrict__ Wht,
                       unsigned short* __restrict__ Wot) {
    int t = blockIdx.x * blockDim.x + threadIdx.x;
    const int S0 = IN_FEATS * N_UNITS;
    const int SH = N_HID * N_UNITS * N_UNITS;
    const int SO = N_UNITS * OUT_FEATS;
    if (t < S0) {
        int k = t >> 8, n = t & 255;
        W0t[(size_t)n * IN_FEATS + k] = f2bf(W0[t]);
    } else if (t < S0 + SH) {
        int u = t - S0;
        int l = u >> 16;
        int r = u & 65535;
        int k = r >> 8, n = r & 255;
        Wht[(size_t)l * 65536 + (size_t)n * N_UNITS + k] = f2bf(Wh[u]);
    } else if (t < S0 + SH + SO) {
        int u = t - S0 - SH;
        int k = u >> 6, n = u & 63;
        Wot[(size_t)n * N_UNITS + k] = f2bf(Wo[u]);
    }
}

// ---------------- bf16 MFMA GEMM: C[M,N] = A[M,K] @ Bt[N,K]^T ----------------
// BM=BN=64, BK=32, 256 threads = 4 waves in 2x2; wave tile 32x32.

template<bool OUT_BF16>
__global__ __launch_bounds__(256) void k_mgemm(const unsigned short* __restrict__ A,
                                               const unsigned short* __restrict__ Bt,
                                               void* __restrict__ Cv,
                                               const int M, const int K, const int Nld) {
    constexpr int BM = 64, BN = 64, BK = 32;
    __shared__ unsigned short As[BM * BK];
    __shared__ unsigned short Bs[BN * BK];

    const int tid  = threadIdx.x;
    const int wid  = tid >> 6;
    const int lane = tid & 63;
    const int wr   = wid >> 1;
    const int wc   = wid & 1;
    const int brow = blockIdx.x * BM;
    const int bcol = blockIdx.y * BN;

    const int lr = lane & 15;
    const int lk = lane >> 4;

    const int row = tid >> 2;      // staging row 0..63
    const int slot = tid & 3;      // 16B slot

    f32x4 acc[2][2];
#pragma unroll
    for (int m = 0; m < 2; ++m)
#pragma unroll
        for (int n = 0; n < 2; ++n)
            acc[m][n] = (f32x4){0.f, 0.f, 0.f, 0.f};

    int gra = brow + row; if (gra >= M) gra = M - 1;
    const unsigned short* gpa = A + (size_t)gra * K + slot * 8;
    const unsigned short* gpb = Bt + (size_t)(bcol + row) * K + slot * 8;

    for (int k0 = 0; k0 < K; k0 += BK) {
        __builtin_amdgcn_global_load_lds(
            (const __attribute__((address_space(1))) void*)(gpa + k0),
            (__attribute__((address_space(3))) void*)(As + tid * 8), 16, 0, 0);
        __builtin_amdgcn_global_load_lds(
            (const __attribute__((address_space(1))) void*)(gpb + k0),
            (__attribute__((address_space(3))) void*)(Bs + tid * 8), 16, 0, 0);
        __syncthreads();

        bf16x8 af[2], bfr[2];
#pragma unroll
        for (int m = 0; m < 2; ++m)
            af[m] = *reinterpret_cast<const bf16x8*>(&As[(wr * 32 + m * 16 + lr) * BK + lk * 8]);
#pragma unroll
        for (int n = 0; n < 2; ++n)
            bfr[n] = *reinterpret_cast<const bf16x8*>(&Bs[(wc * 32 + n * 16 + lr) * BK + lk * 8]);
#pragma unroll
        for (int m = 0; m < 2; ++m)
#pragma unroll
            for (int n = 0; n < 2; ++n)
                acc[m][n] = __builtin_amdgcn_mfma_f32_16x16x32_bf16(af[m], bfr[n], acc[m][n], 0, 0, 0);
        __syncthreads();
    }

#pragma unroll
    for (int m = 0; m < 2; ++m) {
#pragma unroll
        for (int r = 0; r < 4; ++r) {
            int orow = brow + wr * 32 + m * 16 + lk * 4 + r;
            if (orow < M) {
#pragma unroll
                for (int n = 0; n < 2; ++n) {
                    int ocol = bcol + wc * 32 + n * 16 + lr;
                    float v = acc[m][n][r];
                    if (OUT_BF16)
                        ((unsigned short*)Cv)[(size_t)orow * Nld + ocol] = f2bf(v);
                    else
                        ((float*)Cv)[(size_t)orow * Nld + ocol] = v;
                }
            }
        }
    }
}

// ---------------- CSR aggregation + bias + relu + running JK max ----------------
// one wave per node; lane handles 4 feats via uint2 (4x bf16)

__global__ __launch_bounds__(64) void k_agg(const unsigned short* __restrict__ m,
                                            const int* __restrict__ row_ptr,
                                            const int* __restrict__ csr_src,
                                            const float* __restrict__ bias,
                                            unsigned short* __restrict__ x_out,
                                            unsigned short* __restrict__ jk,
                                            int init_jk) {
    int n = blockIdx.x;
    int lane = threadIdx.x;
    int s = row_ptr[n], e = row_ptr[n + 1];
    const uint2* mv = (const uint2*)m;  // row stride 64 uint2

    float a0 = 0.f, a1 = 0.f, a2 = 0.f, a3 = 0.f;
    int i = s;
    for (; i + 3 < e; i += 4) {
        int s0 = csr_src[i], s1 = csr_src[i + 1], s2 = csr_src[i + 2], s3 = csr_src[i + 3];
        uint2 u0 = mv[(size_t)s0 * 64 + lane];
        uint2 u1 = mv[(size_t)s1 * 64 + lane];
        uint2 u2 = mv[(size_t)s2 * 64 + lane];
        uint2 u3 = mv[(size_t)s3 * 64 + lane];
        a0 += bf2f(u0.x & 0xffff) + bf2f(u1.x & 0xffff) + bf2f(u2.x & 0xffff) + bf2f(u3.x & 0xffff);
        a1 += bf2f(u0.x >> 16)    + bf2f(u1.x >> 16)    + bf2f(u2.x >> 16)    + bf2f(u3.x >> 16);
        a2 += bf2f(u0.y & 0xffff) + bf2f(u1.y & 0xffff) + bf2f(u2.y & 0xffff) + bf2f(u3.y & 0xffff);
        a3 += bf2f(u0.y >> 16)    + bf2f(u1.y >> 16)    + bf2f(u2.y >> 16)    + bf2f(u3.y >> 16);
    }
    for (; i < e; ++i) {
        uint2 u = mv[(size_t)csr_src[i] * 64 + lane];
        a0 += bf2f(u.x & 0xffff);
        a1 += bf2f(u.x >> 16);
        a2 += bf2f(u.y & 0xffff);
        a3 += bf2f(u.y >> 16);
    }

    float4 b = ((const float4*)bias)[lane];
    unsigned int h0 = f2bf(fmaxf(a0 + b.x, 0.f));
    unsigned int h1 = f2bf(fmaxf(a1 + b.y, 0.f));
    unsigned int h2 = f2bf(fmaxf(a2 + b.z, 0.f));
    unsigned int h3 = f2bf(fmaxf(a3 + b.w, 0.f));
    uint2 o;
    o.x = h0 | (h1 << 16);
    o.y = h2 | (h3 << 16);

    size_t idx = (size_t)n * 64 + lane;
    ((uint2*)x_out)[idx] = o;
    if (init_jk) {
        ((uint2*)jk)[idx] = o;
    } else {
        uint2 j = ((const uint2*)jk)[idx];
        // all values are >=0 bf16: bit-pattern compare == value compare
        unsigned int j0 = j.x & 0xffff, j1 = j.x >> 16, j2 = j.y & 0xffff, j3 = j.y >> 16;
        j0 = (h0 > j0) ? h0 : j0;
        j1 = (h1 > j1) ? h1 : j1;
        j2 = (h2 > j2) ? h2 : j2;
        j3 = (h3 > j3) ? h3 : j3;
        uint2 w;
        w.x = j0 | (j1 << 16);
        w.y = j2 | (j3 << 16);
        ((uint2*)jk)[idx] = w;
    }
}

// ---------------- final GCN-norm agg + self loop + bias + log_softmax ----------------
// mf in bf16; one wave per node

__global__ __launch_bounds__(256) void k_final(const unsigned short* __restrict__ mf,
                                               const int* __restrict__ row_ptr,
                                               const int* __restrict__ csr_src,
                                               const float* __restrict__ dinv,
                                               const float* __restrict__ invdeg,
                                               const float* __restrict__ bo,
                                               float* __restrict__ out) {
    int wid  = threadIdx.x >> 6;
    int lane = threadIdx.x & 63;
    int n = blockIdx.x * 4 + wid;
    if (n >= N_NODES) return;

    int s = row_ptr[n], e = row_ptr[n + 1];
    float acc = 0.f;
    int i = s;
    for (; i + 3 < e; i += 4) {
        int s0 = csr_src[i], s1 = csr_src[i + 1], s2 = csr_src[i + 2], s3 = csr_src[i + 3];
        acc += bf2f(mf[(size_t)s0 * OUT_FEATS + lane]) * dinv[s0];
        acc += bf2f(mf[(size_t)s1 * OUT_FEATS + lane]) * dinv[s1];
        acc += bf2f(mf[(size_t)s2 * OUT_FEATS + lane]) * dinv[s2];
        acc += bf2f(mf[(size_t)s3 * OUT_FEATS + lane]) * dinv[s3];
    }
    for (; i < e; ++i) {
        int sr = csr_src[i];
        acc += bf2f(mf[(size_t)sr * OUT_FEATS + lane]) * dinv[sr];
    }
    acc *= dinv[n];
    acc += bf2f(mf[(size_t)n * OUT_FEATS + lane]) * invdeg[n] + bo[lane];

    float mx = acc;
#pragma unroll
    for (int off = 32; off; off >>= 1) mx = fmaxf(mx, __shfl_xor(mx, off));
    float ex = __expf(acc - mx);
    float sum = ex;
#pragma unroll
    for (int off = 32; off; off >>= 1) sum += __shfl_xor(sum, off);
    out[(size_t)n * OUT_FEATS + lane] = acc - mx - __logf(sum);
}

// ---------------- launch ----------------

extern "C" void kernel_launch(void* const* d_in, const int* in_sizes, int n_in,
                              void* d_out, int out_size, void* d_ws, size_t ws_size,
                              hipStream_t stream) {
    const float* h  = (const float*)d_in[0];
    const int*   ei = (const int*)d_in[1];
    const float* W0 = (const float*)d_in[2];
    const float* b0 = (const float*)d_in[3];
    const float* Wh = (const float*)d_in[4];
    const float* bh = (const float*)d_in[5];
    const float* Wo = (const float*)d_in[6];
    const float* bo = (const float*)d_in[7];

    const int* src = ei;
    const int* dst = ei + N_EDGES;

    char* p = (char*)d_ws;
    auto carve = [&](size_t bytes) {
        char* r = p;
        p += (bytes + 255) & ~(size_t)255;
        return r;
    };
    int*   deg     = (int*)  carve(N_NODES * 4);
    int*   row_ptr = (int*)  carve((N_NODES + 1) * 4);
    int*   cursor  = (int*)  carve(N_NODES * 4);
    int*   csr_src = (int*)  carve(N_EDGES * 4);
    float* dinv    = (float*)carve(N_NODES * 4);
    float* invdeg  = (float*)carve(N_NODES * 4);
    unsigned short* hb  = (unsigned short*)carve((size_t)N_NODES * IN_FEATS * 2);
    unsigned short* W0t = (unsigned short*)carve((size_t)IN_FEATS * N_UNITS * 2);
    unsigned short* Wht = (unsigned short*)carve((size_t)N_HID * N_UNITS * N_UNITS * 2);
    unsigned short* Wot = (unsigned short*)carve((size_t)N_UNITS * OUT_FEATS * 2);
    unsigned short* m   = (unsigned short*)carve((size_t)N_NODES * N_UNITS * 2);
    unsigned short* x   = (unsigned short*)carve((size_t)N_NODES * N_UNITS * 2);
    unsigned short* jk  = (unsigned short*)carve((size_t)N_NODES * N_UNITS * 2);
    unsigned short* mf  = (unsigned short*)carve((size_t)N_NODES * OUT_FEATS * 2);

    hipMemsetAsync(deg, 0, N_NODES * 4, stream);
    k_hist<<<(N_EDGES + 255) / 256, 256, 0, stream>>>(dst, deg);
    k_scan<<<1, 1024, 0, stream>>>(deg, row_ptr, cursor, dinv, invdeg);
    k_fill<<<(N_EDGES + 255) / 256, 256, 0, stream>>>(src, dst, cursor, csr_src);

    k_cvth<<<(N_NODES * IN_FEATS / 4 + 255) / 256, 256, 0, stream>>>(h, hb);
    {
        int total = IN_FEATS * N_UNITS + N_HID * N_UNITS * N_UNITS + N_UNITS * OUT_FEATS;
        k_cvtw<<<(total + 255) / 256, 256, 0, stream>>>(W0, Wh, Wo, W0t, Wht, Wot);
    }

    const int GBM = (N_NODES + 63) / 64;  // 157

    // layer 0: m = hb @ W0t^T
    {
        dim3 g(GBM, N_UNITS / 64);
        k_mgemm<true><<<g, 256, 0, stream>>>(hb, W0t, m, N_NODES, IN_FEATS, N_UNITS);
    }
    k_agg<<<N_NODES, 64, 0, stream>>>(m, row_ptr, csr_src, b0, x, jk, 1);

    for (int l = 0; l < N_HID; ++l) {
        dim3 g(GBM, N_UNITS / 64);
        k_mgemm<true><<<g, 256, 0, stream>>>(x, Wht + (size_t)l * N_UNITS * N_UNITS,
                                             m, N_NODES, N_UNITS, N_UNITS);
        k_agg<<<N_NODES, 64, 0, stream>>>(m, row_ptr, csr_src, bh + (size_t)l * N_UNITS,
                                          x, jk, 0);
    }

    // final: mf = jk @ Wot^T (bf16 out)
    {
        dim3 g(GBM, 1);
        k_mgemm<true><<<g, 256, 0, stream>>>(jk, Wot, mf, N_NODES, N_UNITS, OUT_FEATS);
    }
    k_final<<<(N_NODES + 3) / 4, 256, 0, stream>>>(mf, row_ptr, csr_src, dinv, invdeg,
                                                   bo, (float*)d_out);
}

// Round 4
// 258.123 us; speedup vs baseline: 2.2637x; 1.0235x over previous
//
#include <hip/hip_runtime.h>
#include <math.h>

#define N_NODES 10000
#define N_EDGES 320000
#define IN_FEATS 512
#define N_UNITS 256
#define OUT_FEATS 64
#define N_HID 5  // hidden Wh layers

typedef __attribute__((ext_vector_type(8))) short bf16x8;
typedef __attribute__((ext_vector_type(4))) float f32x4;

__device__ __forceinline__ unsigned short f2bf(float f) {
    union { float f; unsigned int u; } c; c.f = f;
    unsigned int u = c.u + 0x7FFFu + ((c.u >> 16) & 1u);  // RNE
    return (unsigned short)(u >> 16);
}
__device__ __forceinline__ float bf2f(unsigned int b) {
    union { unsigned int u; float f; } c; c.u = (b & 0xffffu) << 16;
    return c.f;
}

// ---------------- fused setup: deg histogram + h->bf16 + weights->bf16 transposed ----------------

__global__ void k_setup(const int* __restrict__ dst, int* __restrict__ deg,
                        const float* __restrict__ h, unsigned short* __restrict__ hb,
                        const float* __restrict__ W0, const float* __restrict__ Wh,
                        const float* __restrict__ Wo,
                        unsigned short* __restrict__ W0t, unsigned short* __restrict__ Wht,
                        unsigned short* __restrict__ Wot) {
    const int R1 = N_EDGES;                          // histogram
    const int R2 = N_NODES * IN_FEATS / 4;           // h convert (float4)
    const int S0 = IN_FEATS * N_UNITS;
    const int SH = N_HID * N_UNITS * N_UNITS;
    const int SO = N_UNITS * OUT_FEATS;
    int t = blockIdx.x * blockDim.x + threadIdx.x;
    if (t < R1) {
        atomicAdd(&deg[dst[t]], 1);
    } else if (t < R1 + R2) {
        int u = t - R1;
        float4 v = reinterpret_cast<const float4*>(h)[u];
        ushort4 o;
        o.x = f2bf(v.x); o.y = f2bf(v.y); o.z = f2bf(v.z); o.w = f2bf(v.w);
        reinterpret_cast<ushort4*>(hb)[u] = o;
    } else {
        int u = t - R1 - R2;
        if (u < S0) {
            int k = u >> 8, n = u & 255;
            W0t[(size_t)n * IN_FEATS + k] = f2bf(W0[u]);
        } else if (u < S0 + SH) {
            int w = u - S0;
            int l = w >> 16;
            int r = w & 65535;
            int k = r >> 8, n = r & 255;
            Wht[(size_t)l * 65536 + (size_t)n * N_UNITS + k] = f2bf(Wh[w]);
        } else if (u < S0 + SH + SO) {
            int w = u - S0 - SH;
            int k = w >> 6, n = w & 63;
            Wot[(size_t)n * N_UNITS + k] = f2bf(Wo[w]);
        }
    }
}

// ---------------- scan: one 1024-thread block, 10/thread, 3 barriers ----------------

__global__ __launch_bounds__(1024) void k_scan(const int* __restrict__ deg,
                                               int* __restrict__ row_ptr,
                                               int* __restrict__ cursor,
                                               float* __restrict__ dinv,
                                               float* __restrict__ invdeg) {
    __shared__ int wsum[16];
    const int PER = 10;
    int t = threadIdx.x;
    int lane = t & 63, wid = t >> 6;
    int base = t * PER;

    int v[PER];
    int s = 0;
#pragma unroll
    for (int j = 0; j < PER; ++j) {
        int i = base + j;
        int d = (i < N_NODES) ? deg[i] : 0;
        v[j] = s;
        s += d;
    }
    int inc = s;
#pragma unroll
    for (int off = 1; off < 64; off <<= 1) {
        int y = __shfl_up(inc, off);
        if (lane >= off) inc += y;
    }
    if (lane == 63) wsum[wid] = inc;
    __syncthreads();
    if (wid == 0) {
        int w = (lane < 16) ? wsum[lane] : 0;
#pragma unroll
        for (int off = 1; off < 16; off <<= 1) {
            int y = __shfl_up(w, off);
            if (lane >= off) w += y;
        }
        if (lane < 16) wsum[lane] = w;
    }
    __syncthreads();
    int wave_excl = (wid == 0) ? 0 : wsum[wid - 1];
    int thread_excl = wave_excl + (inc - s);

#pragma unroll
    for (int j = 0; j < PER; ++j) {
        int i = base + j;
        if (i < N_NODES) {
            int rp = thread_excl + v[j];
            row_ptr[i] = rp;
            cursor[i]  = rp;
            int d = ((j + 1 < PER) ? v[j + 1] : s) - v[j];
            float dd = (float)(d + 1);
            dinv[i]   = rsqrtf(dd);
            invdeg[i] = 1.0f / dd;
        }
    }
    if (t == 1023) row_ptr[N_NODES] = thread_excl + s;
}

__global__ void k_fill(const int* __restrict__ src, const int* __restrict__ dst,
                       int* __restrict__ cursor, int* __restrict__ csr_src) {
    int e = blockIdx.x * blockDim.x + threadIdx.x;
    if (e < N_EDGES) {
        int p = atomicAdd(&cursor[dst[e]], 1);
        csr_src[p] = src[e];
    }
}

// ---------------- layer-0 GEMM (K=512): 64x64 tile, BK=32, 2-phase dbuf, swizzled LDS ----------------
// C[M,N] = A[M,K] @ Bt[N,K]^T, bf16 out.

__global__ __launch_bounds__(256) void k_mgemm(const unsigned short* __restrict__ A,
                                               const unsigned short* __restrict__ Bt,
                                               unsigned short* __restrict__ C,
                                               const int M, const int K, const int Nld) {
    constexpr int BM = 64, BN = 64, BK = 32;
    __shared__ unsigned short As[2][BM * BK];
    __shared__ unsigned short Bs[2][BN * BK];

    const int tid  = threadIdx.x;
    const int wid  = tid >> 6;
    const int lane = tid & 63;
    const int wr   = wid >> 1;
    const int wc   = wid & 1;
    const int brow = blockIdx.x * BM;
    const int bcol = blockIdx.y * BN;

    const int lr = lane & 15;
    const int lk = lane >> 4;

    const int row  = tid >> 2;                 // staging row 0..63
    const int slot = tid & 3;                  // 16B slot within row
    const int sslot = slot ^ ((row >> 1) & 3); // swizzled source slot (rule 21: src + read, LDS linear)

    int gra = brow + row; if (gra >= M) gra = M - 1;
    const unsigned short* gpa = A + (size_t)gra * K + sslot * 8;
    const unsigned short* gpb = Bt + (size_t)(bcol + row) * K + sslot * 8;

    f32x4 acc[2][2];
#pragma unroll
    for (int m = 0; m < 2; ++m)
#pragma unroll
        for (int n = 0; n < 2; ++n)
            acc[m][n] = (f32x4){0.f, 0.f, 0.f, 0.f};

#define STAGE(buf, k0)                                                                      \
    do {                                                                                    \
        __builtin_amdgcn_global_load_lds(                                                   \
            (const __attribute__((address_space(1))) void*)(gpa + (k0)),                    \
            (__attribute__((address_space(3))) void*)(&As[(buf)][tid * 8]), 16, 0, 0);      \
        __builtin_amdgcn_global_load_lds(                                                   \
            (const __attribute__((address_space(1))) void*)(gpb + (k0)),                    \
            (__attribute__((address_space(3))) void*)(&Bs[(buf)][tid * 8]), 16, 0, 0);      \
    } while (0)

    STAGE(0, 0);
    __syncthreads();

    const int nk = K / BK;
    for (int kt = 0; kt < nk; ++kt) {
        const int cur = kt & 1;
        if (kt + 1 < nk) STAGE(cur ^ 1, (kt + 1) * BK);  // loads fly during MFMA

        bf16x8 af[2], bfr[2];
#pragma unroll
        for (int m = 0; m < 2; ++m) {
            int ra = wr * 32 + m * 16 + lr;
            af[m] = *reinterpret_cast<const bf16x8*>(&As[cur][ra * BK + (lk ^ ((ra >> 1) & 3)) * 8]);
        }
#pragma unroll
        for (int n = 0; n < 2; ++n) {
            int rb = wc * 32 + n * 16 + lr;
            bfr[n] = *reinterpret_cast<const bf16x8*>(&Bs[cur][rb * BK + (lk ^ ((rb >> 1) & 3)) * 8]);
        }
#pragma unroll
        for (int m = 0; m < 2; ++m)
#pragma unroll
            for (int n = 0; n < 2; ++n)
                acc[m][n] = __builtin_amdgcn_mfma_f32_16x16x32_bf16(af[m], bfr[n], acc[m][n], 0, 0, 0);
        __syncthreads();  // drains vmcnt(0): next-tile DMA landed; prev reads done
    }
#undef STAGE

#pragma unroll
    for (int m = 0; m < 2; ++m) {
#pragma unroll
        for (int r = 0; r < 4; ++r) {
            int orow = brow + wr * 32 + m * 16 + lk * 4 + r;
            if (orow < M) {
#pragma unroll
                for (int n = 0; n < 2; ++n) {
                    int ocol = bcol + wc * 32 + n * 16 + lr;
                    C[(size_t)orow * Nld + ocol] = f2bf(acc[m][n][r]);
                }
            }
        }
    }
}

// ---------------- weight-stationary GEMM (K=256 fixed): full-K in LDS, ONE barrier ----------------
// grid: (M/64, N/64). Each block: B-strip[64][256] + A-tile[64][256] in LDS (64 KB), swizzled.
// wave w computes rows [w*16, w*16+16) x all 64 cols: 32 MFMA, 40 ds_read_b128, no inner barriers.

__global__ __launch_bounds__(256) void k_wgemm(const unsigned short* __restrict__ A,
                                               const unsigned short* __restrict__ Bt,
                                               unsigned short* __restrict__ C,
                                               const int M, const int Nld) {
    constexpr int K = 256;
    __shared__ unsigned short As[64 * K];
    __shared__ unsigned short Bs[64 * K];

    const int tid  = threadIdx.x;
    const int wid  = tid >> 6;
    const int lane = tid & 63;
    const int lr   = lane & 15;
    const int lk   = lane >> 4;
    const int brow = blockIdx.x * 64;
    const int bcol = blockIdx.y * 64;

    // stage: 64 rows x 32 slots (16B) each; source slot swizzled, LDS linear (rule 21)
#pragma unroll
    for (int p = 0; p < 8; ++p) {
        int i = p * 256 + tid;
        int row = i >> 5, s = i & 31;
        int gr = brow + row; if (gr >= M) gr = M - 1;
        const unsigned short* gp = A + (size_t)gr * K + ((s ^ (row & 7)) * 8);
        __builtin_amdgcn_global_load_lds(
            (const __attribute__((address_space(1))) void*)gp,
            (__attribute__((address_space(3))) void*)(As + i * 8), 16, 0, 0);
    }
#pragma unroll
    for (int p = 0; p < 8; ++p) {
        int i = p * 256 + tid;
        int row = i >> 5, s = i & 31;
        const unsigned short* gp = Bt + (size_t)(bcol + row) * K + ((s ^ (row & 7)) * 8);
        __builtin_amdgcn_global_load_lds(
            (const __attribute__((address_space(1))) void*)gp,
            (__attribute__((address_space(3))) void*)(Bs + i * 8), 16, 0, 0);
    }
    __syncthreads();  // the only barrier

    f32x4 acc[4];
#pragma unroll
    for (int n = 0; n < 4; ++n) acc[n] = (f32x4){0.f, 0.f, 0.f, 0.f};

    const int ra = (wid << 4) + lr;
    const unsigned short* Arow = As + ra * K;
    const int e = lr & 7;
#pragma unroll
    for (int kk = 0; kk < 8; ++kk) {
        bf16x8 av = *reinterpret_cast<const bf16x8*>(&Arow[(((kk << 2) + lk) ^ e) * 8]);
#pragma unroll
        for (int n = 0; n < 4; ++n) {
            const unsigned short* Brow = Bs + ((n << 4) + lr) * K;
            bf16x8 bv = *reinterpret_cast<const bf16x8*>(&Brow[(((kk << 2) + lk) ^ e) * 8]);
            acc[n] = __builtin_amdgcn_mfma_f32_16x16x32_bf16(av, bv, acc[n], 0, 0, 0);
        }
    }

#pragma unroll
    for (int n = 0; n < 4; ++n) {
#pragma unroll
        for (int r = 0; r < 4; ++r) {
            int orow = brow + (wid << 4) + (lk << 2) + r;
            if (orow < M) {
                int ocol = bcol + (n << 4) + lr;
                C[(size_t)orow * Nld + ocol] = f2bf(acc[n][r]);
            }
        }
    }
}

// ---------------- CSR aggregation + bias + relu + running JK max ----------------
// 8 nodes per 256-thread block; 32 lanes per node, uint4 (8 bf16) per lane

__global__ __launch_bounds__(256) void k_agg(const unsigned short* __restrict__ m,
                                             const int* __restrict__ row_ptr,
                                             const int* __restrict__ csr_src,
                                             const float* __restrict__ bias,
                                             unsigned short* __restrict__ x_out,
                                             unsigned short* __restrict__ jk,
                                             int init_jk) {
    int half = threadIdx.x >> 5;
    int lane = threadIdx.x & 31;
    int n = blockIdx.x * 8 + half;          // N_NODES = 1250*8 exactly
    int s = row_ptr[n], e = row_ptr[n + 1];
    const uint4* mv = (const uint4*)m;      // 32 uint4 per row

    float a[8];
#pragma unroll
    for (int j = 0; j < 8; ++j) a[j] = 0.f;

#define ACC8(u)                                        \
    do {                                               \
        a[0] += bf2f((u).x); a[1] += bf2f((u).x >> 16);\
        a[2] += bf2f((u).y); a[3] += bf2f((u).y >> 16);\
        a[4] += bf2f((u).z); a[5] += bf2f((u).z >> 16);\
        a[6] += bf2f((u).w); a[7] += bf2f((u).w >> 16);\
    } while (0)

    int i = s;
    for (; i + 3 < e; i += 4) {
        int s0 = csr_src[i], s1 = csr_src[i + 1], s2 = csr_src[i + 2], s3 = csr_src[i + 3];
        uint4 u0 = mv[(size_t)s0 * 32 + lane];
        uint4 u1 = mv[(size_t)s1 * 32 + lane];
        uint4 u2 = mv[(size_t)s2 * 32 + lane];
        uint4 u3 = mv[(size_t)s3 * 32 + lane];
        ACC8(u0); ACC8(u1); ACC8(u2); ACC8(u3);
    }
    for (; i < e; ++i) {
        uint4 u = mv[(size_t)csr_src[i] * 32 + lane];
        ACC8(u);
    }
#undef ACC8

    float4 b0 = ((const float4*)bias)[lane * 2];
    float4 b1 = ((const float4*)bias)[lane * 2 + 1];
    unsigned int hh[8];
    hh[0] = f2bf(fmaxf(a[0] + b0.x, 0.f));
    hh[1] = f2bf(fmaxf(a[1] + b0.y, 0.f));
    hh[2] = f2bf(fmaxf(a[2] + b0.z, 0.f));
    hh[3] = f2bf(fmaxf(a[3] + b0.w, 0.f));
    hh[4] = f2bf(fmaxf(a[4] + b1.x, 0.f));
    hh[5] = f2bf(fmaxf(a[5] + b1.y, 0.f));
    hh[6] = f2bf(fmaxf(a[6] + b1.z, 0.f));
    hh[7] = f2bf(fmaxf(a[7] + b1.w, 0.f));
    uint4 o;
    o.x = hh[0] | (hh[1] << 16);
    o.y = hh[2] | (hh[3] << 16);
    o.z = hh[4] | (hh[5] << 16);
    o.w = hh[6] | (hh[7] << 16);

    size_t idx = (size_t)n * 32 + lane;
    ((uint4*)x_out)[idx] = o;
    if (init_jk) {
        ((uint4*)jk)[idx] = o;
    } else {
        uint4 j = ((const uint4*)jk)[idx];
        // post-relu bf16 >= 0: bit compare == value compare
        auto mx2 = [](unsigned int nw, unsigned int od) {
            unsigned int lo_n = nw & 0xffffu, lo_o = od & 0xffffu;
            unsigned int hi_n = nw >> 16,     hi_o = od >> 16;
            unsigned int lo = lo_n > lo_o ? lo_n : lo_o;
            unsigned int hi = hi_n > hi_o ? hi_n : hi_o;
            return lo | (hi << 16);
        };
        uint4 w;
        w.x = mx2(o.x, j.x); w.y = mx2(o.y, j.y);
        w.z = mx2(o.z, j.z); w.w = mx2(o.w, j.w);
        ((uint4*)jk)[idx] = w;
    }
}

// ---------------- final GCN-norm agg + self loop + bias + log_softmax ----------------

__global__ __launch_bounds__(256) void k_final(const unsigned short* __restrict__ mf,
                                               const int* __restrict__ row_ptr,
                                               const int* __restrict__ csr_src,
                                               const float* __restrict__ dinv,
                                               const float* __restrict__ invdeg,
                                               const float* __restrict__ bo,
                                               float* __restrict__ out) {
    int wid  = threadIdx.x >> 6;
    int lane = threadIdx.x & 63;
    int n = blockIdx.x * 4 + wid;
    if (n >= N_NODES) return;

    int s = row_ptr[n], e = row_ptr[n + 1];
    float acc = 0.f;
    int i = s;
    for (; i + 3 < e; i += 4) {
        int s0 = csr_src[i], s1 = csr_src[i + 1], s2 = csr_src[i + 2], s3 = csr_src[i + 3];
        acc += bf2f(mf[(size_t)s0 * OUT_FEATS + lane]) * dinv[s0];
        acc += bf2f(mf[(size_t)s1 * OUT_FEATS + lane]) * dinv[s1];
        acc += bf2f(mf[(size_t)s2 * OUT_FEATS + lane]) * dinv[s2];
        acc += bf2f(mf[(size_t)s3 * OUT_FEATS + lane]) * dinv[s3];
    }
    for (; i < e; ++i) {
        int sr = csr_src[i];
        acc += bf2f(mf[(size_t)sr * OUT_FEATS + lane]) * dinv[sr];
    }
    acc *= dinv[n];
    acc += bf2f(mf[(size_t)n * OUT_FEATS + lane]) * invdeg[n] + bo[lane];

    float mx = acc;
#pragma unroll
    for (int off = 32; off; off >>= 1) mx = fmaxf(mx, __shfl_xor(mx, off));
    float ex = __expf(acc - mx);
    float sum = ex;
#pragma unroll
    for (int off = 32; off; off >>= 1) sum += __shfl_xor(sum, off);
    out[(size_t)n * OUT_FEATS + lane] = acc - mx - __logf(sum);
}

// ---------------- launch ----------------

extern "C" void kernel_launch(void* const* d_in, const int* in_sizes, int n_in,
                              void* d_out, int out_size, void* d_ws, size_t ws_size,
                              hipStream_t stream) {
    const float* h  = (const float*)d_in[0];
    const int*   ei = (const int*)d_in[1];
    const float* W0 = (const float*)d_in[2];
    const float* b0 = (const float*)d_in[3];
    const float* Wh = (const float*)d_in[4];
    const float* bh = (const float*)d_in[5];
    const float* Wo = (const float*)d_in[6];
    const float* bo = (const float*)d_in[7];

    const int* src = ei;
    const int* dst = ei + N_EDGES;

    char* p = (char*)d_ws;
    auto carve = [&](size_t bytes) {
        char* r = p;
        p += (bytes + 255) & ~(size_t)255;
        return r;
    };
    int*   deg     = (int*)  carve(N_NODES * 4);
    int*   row_ptr = (int*)  carve((N_NODES + 1) * 4);
    int*   cursor  = (int*)  carve(N_NODES * 4);
    int*   csr_src = (int*)  carve(N_EDGES * 4);
    float* dinv    = (float*)carve(N_NODES * 4);
    float* invdeg  = (float*)carve(N_NODES * 4);
    unsigned short* hb  = (unsigned short*)carve((size_t)N_NODES * IN_FEATS * 2);
    unsigned short* W0t = (unsigned short*)carve((size_t)IN_FEATS * N_UNITS * 2);
    unsigned short* Wht = (unsigned short*)carve((size_t)N_HID * N_UNITS * N_UNITS * 2);
    unsigned short* Wot = (unsigned short*)carve((size_t)N_UNITS * OUT_FEATS * 2);
    unsigned short* m   = (unsigned short*)carve((size_t)N_NODES * N_UNITS * 2);
    unsigned short* x   = (unsigned short*)carve((size_t)N_NODES * N_UNITS * 2);
    unsigned short* jk  = (unsigned short*)carve((size_t)N_NODES * N_UNITS * 2);
    unsigned short* mf  = (unsigned short*)carve((size_t)N_NODES * OUT_FEATS * 2);

    hipMemsetAsync(deg, 0, N_NODES * 4, stream);
    {
        const int total = N_EDGES + N_NODES * IN_FEATS / 4 +
                          IN_FEATS * N_UNITS + N_HID * N_UNITS * N_UNITS + N_UNITS * OUT_FEATS;
        k_setup<<<(total + 255) / 256, 256, 0, stream>>>(dst, deg, h, hb, W0, Wh, Wo,
                                                         W0t, Wht, Wot);
    }
    k_scan<<<1, 1024, 0, stream>>>(deg, row_ptr, cursor, dinv, invdeg);
    k_fill<<<(N_EDGES + 255) / 256, 256, 0, stream>>>(src, dst, cursor, csr_src);

    const int GBM = (N_NODES + 63) / 64;  // 157

    // layer 0: m = hb @ W0t^T  (K=512, dbuf k-loop)
    {
        dim3 g(GBM, N_UNITS / 64);
        k_mgemm<<<g, 256, 0, stream>>>(hb, W0t, m, N_NODES, IN_FEATS, N_UNITS);
    }
    k_agg<<<N_NODES / 8, 256, 0, stream>>>(m, row_ptr, csr_src, b0, x, jk, 1);

    // hidden layers: weight-stationary K=256
    for (int l = 0; l < N_HID; ++l) {
        dim3 g(GBM, N_UNITS / 64);
        k_wgemm<<<g, 256, 0, stream>>>(x, Wht + (size_t)l * N_UNITS * N_UNITS, m,
                                       N_NODES, N_UNITS);
        k_agg<<<N_NODES / 8, 256, 0, stream>>>(m, row_ptr, csr_src, bh + (size_t)l * N_UNITS,
                                               x, jk, 0);
    }

    // final: mf = jk @ Wot^T (K=256, N=64)
    {
        dim3 g(GBM, 1);
        k_wgemm<<<g, 256, 0, stream>>>(jk, Wot, mf, N_NODES, OUT_FEATS);
    }
    k_final<<<(N_NODES + 3) / 4, 256, 0, stream>>>(mf, row_ptr, csr_src, dinv, invdeg,
                                                   bo, (float*)d_out);
}